// Round 12
// baseline (1510.993 us; speedup 1.0000x reference)
//
#include <hip/hip_runtime.h>
#include <cstdint>
#include <cstddef>
#include <cmath>

#define B_N   32768
#define D_DIM 512
#define NC_N  64
#define NTRI  2016      /* packed upper-triangle skew columns (i<j) */
#define NP    2176      /* 2016 tri + 64 w_z + 8 g_u + 8 g_v + 80 pad (17*128) */
#define Q0    2016
#define U0    2080
#define V0    2088
#define KP    1536      /* [zh|zh|zl] . [wh|wl|wh] f16 split, K=3*512 */
#define KT_N  24        /* KP/64 */
#define TEPS  1e-3f
#define SC1   0x1.0p-22f  /* undo 2^11 * 2^11 input scaling */

typedef unsigned short u16;
typedef _Float16 f16;
typedef __attribute__((ext_vector_type(8))) _Float16 f16x8;
typedef __attribute__((ext_vector_type(4))) float f32x4;
typedef __attribute__((ext_vector_type(2))) float f32x2;

__device__ __forceinline__ u16 h_of(float x) { f16 h = (f16)x; return *reinterpret_cast<u16*>(&h); }
__device__ __forceinline__ float f_of_h(u16 u) { f16 h = *reinterpret_cast<f16*>(&u); return (float)h; }
__device__ __forceinline__ float rdlane(float x, int k) {
    return __int_as_float(__builtin_amdgcn_readlane(__float_as_int(x), k));
}
__device__ __forceinline__ float frcp(float x) {
    float r = __builtin_amdgcn_rcpf(x);
    return r * fmaf(-x, r, 2.0f);
}
__device__ __forceinline__ void split2(float x, u16& h, u16& l) {
    float s = x * 2048.0f;           // exact
    h = h_of(s);
    l = h_of(s - f_of_h(h));
}

// ---------------- prep: B' rows -> [NP][1536] f16 = [wh|wl|wh]
// rows 0..2015 (packed pair p <-> (i<j)): 0.25*(w_t[j*64+i] - w_t[i*64+j]).
// rows 2016..2079: w_z ; 2080..2087: g_u ; 2088..2095: g_v ; rest 0.
__global__ __launch_bounds__(256) void prep_w_kernel(
    const float* __restrict__ wt, const float* __restrict__ wz,
    const float* __restrict__ gu, const float* __restrict__ gv,
    u16* __restrict__ dst)
{
    int t = blockIdx.x * 256 + threadIdx.x;
    if (t >= NP * 128) return;
    int row = t >> 7;
    int c4  = (t & 127) << 2;
    float4 v = make_float4(0.f, 0.f, 0.f, 0.f);
    if (row < NTRI) {
        int p = row;
        int i = (int)((127.0 - sqrt(16129.0 - 8.0 * (double)p)) * 0.5);
        if (i < 0) i = 0; if (i > 62) i = 62;
        while (i > 0 && (i * (127 - i)) / 2 > p) --i;
        while (((i + 1) * (126 - i)) / 2 <= p) ++i;
        int j = p - (i * (127 - i)) / 2 + i + 1;
        float4 a = *(const float4*)(wt + (size_t)(j * 64 + i) * 512 + c4);
        float4 b = *(const float4*)(wt + (size_t)(i * 64 + j) * 512 + c4);
        v.x = 0.25f * (a.x - b.x);
        v.y = 0.25f * (a.y - b.y);
        v.z = 0.25f * (a.z - b.z);
        v.w = 0.25f * (a.w - b.w);
    }
    else if (row < U0)        v = *(const float4*)(wz + (size_t)(row - Q0) * 512 + c4);
    else if (row < V0)        v = *(const float4*)(gu + (size_t)(row - U0) * 512 + c4);
    else if (row < V0 + 8)    v = *(const float4*)(gv + (size_t)(row - V0) * 512 + c4);
    ushort4 hv, lv;
    split2(v.x, hv.x, lv.x); split2(v.y, hv.y, lv.y);
    split2(v.z, hv.z, lv.z); split2(v.w, hv.w, lv.w);
    u16* base = dst + (size_t)row * KP + c4;
    *(ushort4*)(base)        = hv;
    *(ushort4*)(base + 512)  = lv;
    *(ushort4*)(base + 1024) = hv;
}

// ---------------- prep: z chunk -> [CB][1536] f16 = [zh|zh|zl]
__global__ __launch_bounds__(256) void prep_z_kernel(
    const float* __restrict__ z, u16* __restrict__ dst, int chunkStart, int CB)
{
    int t = blockIdx.x * 256 + threadIdx.x;
    if (t >= CB * 128) return;
    int row = t >> 7;
    int c4  = (t & 127) << 2;
    float4 v = *(const float4*)(z + (size_t)(chunkStart + row) * 512 + c4);
    ushort4 hv, lv;
    split2(v.x, hv.x, lv.x); split2(v.y, hv.y, lv.y);
    split2(v.z, hv.z, lv.z); split2(v.w, hv.w, lv.w);
    u16* base = dst + (size_t)row * KP + c4;
    *(ushort4*)(base)        = hv;
    *(ushort4*)(base + 512)  = hv;
    *(ushort4*)(base + 1024) = lv;
}

// ---------------- GEMM: C[CB][NP] f32 = (A[CB][KP] * B[NP][KP]^T) * 2^-22
// r9-proven 128x128 tile, BK=64, 4 waves (2x2), 16x16x32 f16 MFMA,
// global_load_lds(16B), bijective XCD swizzle, non-temporal C stores.
__global__ __launch_bounds__(256) void gemm_kernel(
    const u16* __restrict__ A, const u16* __restrict__ Bw, float* __restrict__ C)
{
    __shared__ alignas(16) u16 As[128 * 64];
    __shared__ alignas(16) u16 Bs[128 * 64];
    const int t    = threadIdx.x;
    const int lane = t & 63;
    const int w    = t >> 6;
    const int wr   = w >> 1, wc = w & 1;

    const int nwg = gridDim.x * gridDim.y;
    int flat = blockIdx.y * gridDim.x + blockIdx.x;
    if ((nwg & 7) == 0) {
        const int cpx = nwg >> 3;
        flat = (flat & 7) * cpx + (flat >> 3);
    }
    const int bx = flat % gridDim.x;
    const int by = flat / gridDim.x;
    const size_t m0 = (size_t)by * 128;
    const size_t n0 = (size_t)bx * 128;

    const char* Ab = (const char*)A  + (m0 + (size_t)(t >> 3)) * (KP * 2) + (size_t)(t & 7) * 16;
    const char* Bb = (const char*)Bw + (n0 + (size_t)(t >> 3)) * (KP * 2) + (size_t)(t & 7) * 16;
    char* AsB = (char*)&As[0];
    char* BsB = (char*)&Bs[0];

    f32x4 acc[4][4];
    #pragma unroll
    for (int i = 0; i < 4; ++i)
        #pragma unroll
        for (int j = 0; j < 4; ++j)
            acc[i][j] = (f32x4){0.f, 0.f, 0.f, 0.f};

    const int lr = lane & 15;
    const int lk = (lane >> 4) * 8;

    #pragma unroll 1
    for (int kt = 0; kt < KT_N; ++kt) {
        __syncthreads();
        const size_t koff = (size_t)kt * 128;
        #pragma unroll
        for (int cc = 0; cc < 4; ++cc) {
            __builtin_amdgcn_global_load_lds(
                (const __attribute__((address_space(1))) unsigned int*)(Ab + (size_t)cc * (32 * KP * 2) + koff),
                (__attribute__((address_space(3))) unsigned int*)(AsB + cc * 4096 + w * 1024),
                16, 0, 0);
            __builtin_amdgcn_global_load_lds(
                (const __attribute__((address_space(1))) unsigned int*)(Bb + (size_t)cc * (32 * KP * 2) + koff),
                (__attribute__((address_space(3))) unsigned int*)(BsB + cc * 4096 + w * 1024),
                16, 0, 0);
        }
        asm volatile("s_waitcnt vmcnt(0)" ::: "memory");
        __syncthreads();
        #pragma unroll
        for (int kk = 0; kk < 64; kk += 32) {
            f16x8 af[4], bf[4];
            #pragma unroll
            for (int i = 0; i < 4; ++i) {
                af[i] = *(const f16x8*)&As[(wr * 64 + i * 16 + lr) * 64 + kk + lk];
                bf[i] = *(const f16x8*)&Bs[(wc * 64 + i * 16 + lr) * 64 + kk + lk];
            }
            #pragma unroll
            for (int i = 0; i < 4; ++i)
                #pragma unroll
                for (int j = 0; j < 4; ++j)
                    acc[i][j] = __builtin_amdgcn_mfma_f32_16x16x32_f16(af[i], bf[j], acc[i][j], 0, 0, 0);
        }
    }
    const int fq = lane >> 4;
    const int fr = lane & 15;
    #pragma unroll
    for (int i = 0; i < 4; ++i) {
        #pragma unroll
        for (int j = 0; j < 4; ++j) {
            size_t crow = m0 + (size_t)(wr * 64 + i * 16 + fq * 4);
            size_t ccol = n0 + (size_t)(wc * 64 + j * 16 + fr);
            #pragma unroll
            for (int r = 0; r < 4; ++r)
                __builtin_nontemporal_store(acc[i][j][r] * SC1, &C[(crow + r) * NP + ccol]);
        }
    }
}

// ---------------- per-sample Cayley solve + router — ILP-2
// TWO samples per wave (1 wave per 64-thread block). The packed Gauss-Jordan
// is a serial readlane->pk_fma chain (r11: 46% issue density at ~1.8 resident
// waves/SIMD); interleaving two independent sample-streams inside one wave
// fills the RAW-hazard bubbles without needing more resident waves.
// Plain __launch_bounds__(64): full register budget; ~180 VGPR expected,
// NO spill (WRITE_SIZE is the tripwire). Shared loads (cq, gout) serve both.
// Numerics per sample identical to r11 (proven absmax 3.9e-3).
__global__ __launch_bounds__(64) void solve_kernel(
    const float* __restrict__ z, const float* __restrict__ bz,
    const float* __restrict__ gout, const float* __restrict__ cq,
    const float* __restrict__ G, float* __restrict__ rw, float* __restrict__ kc,
    int chunkStart)
{
    const int lane = threadIdx.x;
    const int slA  = blockIdx.x * 2;
    const int slB  = slA + 1;
    const size_t sA = (size_t)chunkStart + slA;
    const size_t sB = (size_t)chunkStart + slB;
    const float c  = 1.0f + TEPS;

    __shared__ alignas(16) float Vs[2][2048];

    const float* GrowA = G + (size_t)slA * NP;
    const float* GrowB = G + (size_t)slB * NP;

    // ---- stage both packed triangles (coalesced float4; wave-local)
    {
        const float4* G4A = (const float4*)GrowA;
        const float4* G4B = (const float4*)GrowB;
        float4* VwA = (float4*)&Vs[0][0];
        float4* VwB = (float4*)&Vs[1][0];
        #pragma unroll
        for (int it = 0; it < 8; ++it) {
            int idx = it * 64 + lane;
            if (idx < NTRI / 4) { VwA[idx] = G4A[idx]; VwB[idx] = G4B[idx]; }
        }
    }

    // ---- r2 = ||z||^2 for both samples
    float r2A, r2B;
    {
        const float4* zrA = (const float4*)(z + sA * 512);
        const float4* zrB = (const float4*)(z + sB * 512);
        float4 a0 = zrA[lane], a1 = zrA[64 + lane];
        float4 b0 = zrB[lane], b1 = zrB[64 + lane];
        r2A = a0.x*a0.x + a0.y*a0.y + a0.z*a0.z + a0.w*a0.w
            + a1.x*a1.x + a1.y*a1.y + a1.z*a1.z + a1.w*a1.w;
        r2B = b0.x*b0.x + b0.y*b0.y + b0.z*b0.z + b0.w*b0.w
            + b1.x*b1.x + b1.y*b1.y + b1.z*b1.z + b1.w*b1.w;
        #pragma unroll
        for (int o = 32; o; o >>= 1) {
            r2A += __shfl_xor(r2A, o);
            r2B += __shfl_xor(r2B, o);
        }
    }

    // ---- q_k for k = lane (shared gout loads)
    float qvA = bz[lane] + GrowA[Q0 + lane];
    float qvB = bz[lane] + GrowB[Q0 + lane];
    #pragma unroll
    for (int r = 0; r < 8; ++r) {
        float go = gout[r * 64 + lane];
        qvA = fmaf(GrowA[U0 + r] * GrowA[V0 + r], go, qvA);
        qvB = fmaf(GrowB[U0 + r] * GrowB[V0 + r], go, qvB);
    }
    const float qorigA = qvA;
    const float qorigB = qvB;

    // ---- gather M rows from LDS triangles into f32x2 pairs (both samples)
    const int ibase = (lane * (127 - lane)) / 2 - lane - 1;
    f32x2 mA[32], mB[32];
    #pragma unroll
    for (int j = 0; j < 64; ++j) {
        const int jbase = (j * (127 - j)) / 2 - j - 1;
        int addr = (j > lane) ? (ibase + j) : (jbase + lane);
        addr = (j == lane) ? 0 : addr;
        float vA = Vs[0][addr];
        float vB = Vs[1][addr];
        float valA = (j > lane) ? vA : -vA;
        float valB = (j > lane) ? vB : -vB;
        valA = (j == lane) ? 0.0f : valA;
        valB = (j == lane) ? 0.0f : valB;
        if (j & 1) { mA[j >> 1].y = valA; mB[j >> 1].y = valB; }
        else       { mA[j >> 1].x = valA; mB[j >> 1].x = valB; }
    }

    // ---- packed Gauss-Jordan, two interleaved streams
    float myinvA = 0.0f, myinvB = 0.0f;
    #pragma unroll
    for (int k = 0; k < 64; ++k) {
        const int kp = k >> 1;
        const float mkA = (k & 1) ? mA[kp].y : mA[kp].x;
        const float mkB = (k & 1) ? mB[kp].y : mB[kp].x;
        float pivA = rdlane(mkA, k) + c;
        float pivB = rdlane(mkB, k) + c;
        float invA = frcp(pivA);
        float invB = frcp(pivB);
        bool isk = (lane == k);
        float fA = isk ? 0.0f : mkA * invA;
        float fB = isk ? 0.0f : mkB * invB;
        myinvA = isk ? invA : myinvA;
        myinvB = isk ? invB : myinvB;
        const float nfA = -fA, nfB = -fB;
        const f32x2 nfA2 = {nfA, nfA}, nfB2 = {nfB, nfB};
        qvA = fmaf(nfA, rdlane(qvA, k), qvA);
        qvB = fmaf(nfB, rdlane(qvB, k), qvB);
        if ((k & 1) == 0) {
            mA[kp].y = fmaf(nfA, rdlane(mA[kp].y, k), mA[kp].y);
            mB[kp].y = fmaf(nfB, rdlane(mB[kp].y, k), mB[kp].y);
        }
        #pragma unroll
        for (int p = kp + 1; p < 32; ++p) {
            f32x2 bcA, bcB;
            bcA.x = rdlane(mA[p].x, k);
            bcA.y = rdlane(mA[p].y, k);
            bcB.x = rdlane(mB[p].x, k);
            bcB.y = rdlane(mB[p].y, k);
            mA[p] = __builtin_elementwise_fma(nfA2, bcA, mA[p]);
            mB[p] = __builtin_elementwise_fma(nfB2, bcB, mB[p]);
        }
        if (k & 1) { mA[kp].y = fA; mB[kp].y = fB; }
        else       { mA[kp].x = fA; mB[kp].x = fB; }
    }
    float yA = qvA * myinvA;
    float yB = qvB * myinvB;

    // ---- one refinement step: r = q - M*y in f64 (re-gather from LDS)
    double rdA = (double)qorigA - (double)c * (double)yA;
    double rdB = (double)qorigB - (double)c * (double)yB;
    #pragma unroll
    for (int j = 0; j < 64; ++j) {
        const int jbase = (j * (127 - j)) / 2 - j - 1;
        int addr = (j > lane) ? (ibase + j) : (jbase + lane);
        addr = (j == lane) ? 0 : addr;
        float vA = Vs[0][addr];
        float vB = Vs[1][addr];
        float valA = (j > lane) ? vA : -vA;
        float valB = (j > lane) ? vB : -vB;
        valA = (j == lane) ? 0.0f : valA;
        valB = (j == lane) ? 0.0f : valB;
        rdA -= (double)valA * (double)rdlane(yA, j);
        rdB -= (double)valB * (double)rdlane(yB, j);
    }
    float rfA = (float)rdA;
    float rfB = (float)rdB;
    #pragma unroll
    for (int k = 0; k < 64; ++k) {
        const float mkA = (k & 1) ? mA[k >> 1].y : mA[k >> 1].x;
        const float mkB = (k & 1) ? mB[k >> 1].y : mB[k >> 1].x;
        rfA = fmaf(-mkA, rdlane(rfA, k), rfA);
        rfB = fmaf(-mkB, rdlane(rfB, k), rfB);
    }
    yA = fmaf(rfA, myinvA, yA);
    yB = fmaf(rfB, myinvB, yB);

    const float vA = 2.0f * c * yA - qorigA;
    const float vB = 2.0f * c * yB - qorigB;

    // ---- scores (lane = chart n), shared cq loads
    float scA = 0.0f, scB = 0.0f;
    const float4* cr = (const float4*)(cq + (size_t)lane * 64);
    #pragma unroll
    for (int j4 = 0; j4 < 16; ++j4) {
        float4 c4 = cr[j4];
        scA = fmaf(c4.x, rdlane(vA, 4 * j4 + 0), scA);
        scB = fmaf(c4.x, rdlane(vB, 4 * j4 + 0), scB);
        scA = fmaf(c4.y, rdlane(vA, 4 * j4 + 1), scA);
        scB = fmaf(c4.y, rdlane(vB, 4 * j4 + 1), scB);
        scA = fmaf(c4.z, rdlane(vA, 4 * j4 + 2), scA);
        scB = fmaf(c4.z, rdlane(vB, 4 * j4 + 2), scB);
        scA = fmaf(c4.w, rdlane(vA, 4 * j4 + 3), scA);
        scB = fmaf(c4.w, rdlane(vB, 4 * j4 + 3), scB);
    }

    // ---- softmax / argmax (both)
    float denA = fmaxf(1.0f - r2A, 1e-3f);
    float denB = fmaxf(1.0f - r2B, 1e-3f);
    float tauA = fmaxf(4.0f * denA, 0.01f);
    float tauB = fmaxf(4.0f * denB, 0.01f);
    float lgA = scA * frcp(tauA);
    float lgB = scB * frcp(tauB);
    float mxA = lgA, mxB = lgB;
    #pragma unroll
    for (int o = 32; o; o >>= 1) {
        mxA = fmaxf(mxA, __shfl_xor(mxA, o));
        mxB = fmaxf(mxB, __shfl_xor(mxB, o));
    }
    float eA = __expf(lgA - mxA);
    float eB = __expf(lgB - mxB);
    float suA = eA, suB = eB;
    #pragma unroll
    for (int o = 32; o; o >>= 1) {
        suA += __shfl_xor(suA, o);
        suB += __shfl_xor(suB, o);
    }
    rw[sA * 64 + lane] = eA * frcp(suA);
    rw[sB * 64 + lane] = eB * frcp(suB);

    unsigned long long balA = __ballot(lgA == mxA);
    unsigned long long balB = __ballot(lgB == mxB);
    if (lane == 0) {
        kc[sA] = (float)(__ffsll(balA) - 1);
        kc[sB] = (float)(__ffsll(balB) - 1);
    }
}

// ---------------- host orchestration
extern "C" void kernel_launch(void* const* d_in, const int* in_sizes, int n_in,
                              void* d_out, int out_size, void* d_ws, size_t ws_size,
                              hipStream_t stream)
{
    const float* z    = (const float*)d_in[0];
    const float* wz   = (const float*)d_in[1];
    const float* bz   = (const float*)d_in[2];
    const float* gout = (const float*)d_in[3];
    const float* gu   = (const float*)d_in[4];
    const float* gv   = (const float*)d_in[5];
    const float* cq   = (const float*)d_in[6];
    const float* wt   = (const float*)d_in[7];

    float* rw = (float*)d_out;
    float* kc = rw + (size_t)B_N * NC_N;

    const size_t whl_b = (size_t)NP * KP * 2;   // ~6.7 MB
    int CB = 128;
    const int cands[9] = {32768, 16384, 8192, 4096, 2048, 1024, 512, 256, 128};
    for (int i = 0; i < 9; ++i) {
        size_t need = whl_b + (size_t)cands[i] * ((size_t)KP * 2 + (size_t)NP * 4);
        if (need <= ws_size) { CB = cands[i]; break; }
    }

    u16*   w_hl = (u16*)d_ws;
    u16*   z_hl = (u16*)((char*)d_ws + whl_b);
    float* G    = (float*)((char*)d_ws + whl_b + (size_t)CB * KP * 2);

    prep_w_kernel<<<NP / 2, 256, 0, stream>>>(wt, wz, gu, gv, w_hl);
    for (int cs = 0; cs < B_N; cs += CB) {
        prep_z_kernel<<<CB / 2, 256, 0, stream>>>(z, z_hl, cs, CB);
        gemm_kernel<<<dim3(NP / 128, CB / 128), 256, 0, stream>>>(z_hl, w_hl, G);
        solve_kernel<<<CB / 2, 64, 0, stream>>>(z, bz, gout, cq, G, rw, kc, cs);
    }
}

// Round 13
// 1366.611 us; speedup vs baseline: 1.1056x; 1.1056x over previous
//
#include <hip/hip_runtime.h>
#include <cstdint>
#include <cstddef>
#include <cmath>

#define B_N   32768
#define D_DIM 512
#define NC_N  64
#define NTRI  2016      /* packed upper-triangle skew columns (i<j) */
#define NP    2176      /* 2016 tri + 64 w_z + 8 g_u + 8 g_v + 80 pad (17*128) */
#define Q0    2016
#define U0    2080
#define V0    2088
#define KP    1536      /* [zh|zh|zl] . [wh|wl|wh] f16 split, K=3*512 */
#define KT_N  24        /* KP/64 */
#define TEPS  1e-3f
#define SC1   0x1.0p-22f  /* undo 2^11 * 2^11 input scaling */

typedef unsigned short u16;
typedef _Float16 f16;
typedef __attribute__((ext_vector_type(8))) _Float16 f16x8;
typedef __attribute__((ext_vector_type(4))) float f32x4;
typedef __attribute__((ext_vector_type(2))) float f32x2;

__device__ __forceinline__ u16 h_of(float x) { f16 h = (f16)x; return *reinterpret_cast<u16*>(&h); }
__device__ __forceinline__ float f_of_h(u16 u) { f16 h = *reinterpret_cast<f16*>(&u); return (float)h; }
__device__ __forceinline__ float rdlane(float x, int k) {
    return __int_as_float(__builtin_amdgcn_readlane(__float_as_int(x), k));
}
__device__ __forceinline__ float frcp(float x) {
    float r = __builtin_amdgcn_rcpf(x);
    return r * fmaf(-x, r, 2.0f);
}
__device__ __forceinline__ void split2(float x, u16& h, u16& l) {
    float s = x * 2048.0f;           // exact
    h = h_of(s);
    l = h_of(s - f_of_h(h));
}

// ---------------- prep: B' rows -> [NP][1536] f16 = [wh|wl|wh]
__global__ __launch_bounds__(256) void prep_w_kernel(
    const float* __restrict__ wt, const float* __restrict__ wz,
    const float* __restrict__ gu, const float* __restrict__ gv,
    u16* __restrict__ dst)
{
    int t = blockIdx.x * 256 + threadIdx.x;
    if (t >= NP * 128) return;
    int row = t >> 7;
    int c4  = (t & 127) << 2;
    float4 v = make_float4(0.f, 0.f, 0.f, 0.f);
    if (row < NTRI) {
        int p = row;
        int i = (int)((127.0 - sqrt(16129.0 - 8.0 * (double)p)) * 0.5);
        if (i < 0) i = 0; if (i > 62) i = 62;
        while (i > 0 && (i * (127 - i)) / 2 > p) --i;
        while (((i + 1) * (126 - i)) / 2 <= p) ++i;
        int j = p - (i * (127 - i)) / 2 + i + 1;
        float4 a = *(const float4*)(wt + (size_t)(j * 64 + i) * 512 + c4);
        float4 b = *(const float4*)(wt + (size_t)(i * 64 + j) * 512 + c4);
        v.x = 0.25f * (a.x - b.x);
        v.y = 0.25f * (a.y - b.y);
        v.z = 0.25f * (a.z - b.z);
        v.w = 0.25f * (a.w - b.w);
    }
    else if (row < U0)        v = *(const float4*)(wz + (size_t)(row - Q0) * 512 + c4);
    else if (row < V0)        v = *(const float4*)(gu + (size_t)(row - U0) * 512 + c4);
    else if (row < V0 + 8)    v = *(const float4*)(gv + (size_t)(row - V0) * 512 + c4);
    ushort4 hv, lv;
    split2(v.x, hv.x, lv.x); split2(v.y, hv.y, lv.y);
    split2(v.z, hv.z, lv.z); split2(v.w, hv.w, lv.w);
    u16* base = dst + (size_t)row * KP + c4;
    *(ushort4*)(base)        = hv;
    *(ushort4*)(base + 512)  = lv;
    *(ushort4*)(base + 1024) = hv;
}

// ---------------- prep: z (FULL batch) -> [B_N][1536] f16 = [zh|zh|zl]
__global__ __launch_bounds__(256) void prep_z_kernel(
    const float* __restrict__ z, u16* __restrict__ dst)
{
    int t = blockIdx.x * 256 + threadIdx.x;
    int row = t >> 7;
    int c4  = (t & 127) << 2;
    float4 v = *(const float4*)(z + (size_t)row * 512 + c4);
    ushort4 hv, lv;
    split2(v.x, hv.x, lv.x); split2(v.y, hv.y, lv.y);
    split2(v.z, hv.z, lv.z); split2(v.w, hv.w, lv.w);
    u16* base = dst + (size_t)row * KP + c4;
    *(ushort4*)(base)        = hv;
    *(ushort4*)(base + 512)  = hv;
    *(ushort4*)(base + 1024) = lv;
}

// ---------------- GEMM body (r9-proven): C[CB][NP] = (A*B^T)*2^-22
// 128x128 tile, BK=64, 4 waves (2x2), 16x16x32 f16 MFMA, gload_lds(16B),
// XCD swizzle over the gemm-block subset, non-temporal C stores.
__device__ __forceinline__ void gemm_body(
    char* smem, const u16* __restrict__ A, const u16* __restrict__ Bw,
    float* __restrict__ C, int gemmBlocks, int bidx)
{
    u16* As = (u16*)smem;            // 16 KB
    u16* Bs = (u16*)(smem + 16384);  // 16 KB
    const int t    = threadIdx.x;
    const int lane = t & 63;
    const int w    = t >> 6;
    const int wr   = w >> 1, wc = w & 1;

    int flat = bidx;
    if ((gemmBlocks & 7) == 0) {
        const int cpx = gemmBlocks >> 3;
        flat = (flat & 7) * cpx + (flat >> 3);
    }
    const int bx = flat % (NP / 128);
    const int by = flat / (NP / 128);
    const size_t m0 = (size_t)by * 128;
    const size_t n0 = (size_t)bx * 128;

    const char* Ab = (const char*)A  + (m0 + (size_t)(t >> 3)) * (KP * 2) + (size_t)(t & 7) * 16;
    const char* Bb = (const char*)Bw + (n0 + (size_t)(t >> 3)) * (KP * 2) + (size_t)(t & 7) * 16;
    char* AsB = (char*)As;
    char* BsB = (char*)Bs;

    f32x4 acc[4][4];
    #pragma unroll
    for (int i = 0; i < 4; ++i)
        #pragma unroll
        for (int j = 0; j < 4; ++j)
            acc[i][j] = (f32x4){0.f, 0.f, 0.f, 0.f};

    const int lr = lane & 15;
    const int lk = (lane >> 4) * 8;

    #pragma unroll 1
    for (int kt = 0; kt < KT_N; ++kt) {
        __syncthreads();
        const size_t koff = (size_t)kt * 128;
        #pragma unroll
        for (int cc = 0; cc < 4; ++cc) {
            __builtin_amdgcn_global_load_lds(
                (const __attribute__((address_space(1))) unsigned int*)(Ab + (size_t)cc * (32 * KP * 2) + koff),
                (__attribute__((address_space(3))) unsigned int*)(AsB + cc * 4096 + w * 1024),
                16, 0, 0);
            __builtin_amdgcn_global_load_lds(
                (const __attribute__((address_space(1))) unsigned int*)(Bb + (size_t)cc * (32 * KP * 2) + koff),
                (__attribute__((address_space(3))) unsigned int*)(BsB + cc * 4096 + w * 1024),
                16, 0, 0);
        }
        asm volatile("s_waitcnt vmcnt(0)" ::: "memory");
        __syncthreads();
        #pragma unroll
        for (int kk = 0; kk < 64; kk += 32) {
            f16x8 af[4], bf[4];
            #pragma unroll
            for (int i = 0; i < 4; ++i) {
                af[i] = *(const f16x8*)&As[(wr * 64 + i * 16 + lr) * 64 + kk + lk];
                bf[i] = *(const f16x8*)&Bs[(wc * 64 + i * 16 + lr) * 64 + kk + lk];
            }
            #pragma unroll
            for (int i = 0; i < 4; ++i)
                #pragma unroll
                for (int j = 0; j < 4; ++j)
                    acc[i][j] = __builtin_amdgcn_mfma_f32_16x16x32_f16(af[i], bf[j], acc[i][j], 0, 0, 0);
        }
    }
    const int fq = lane >> 4;
    const int fr = lane & 15;
    #pragma unroll
    for (int i = 0; i < 4; ++i) {
        #pragma unroll
        for (int j = 0; j < 4; ++j) {
            size_t crow = m0 + (size_t)(wr * 64 + i * 16 + fq * 4);
            size_t ccol = n0 + (size_t)(wc * 64 + j * 16 + fr);
            #pragma unroll
            for (int r = 0; r < 4; ++r)
                __builtin_nontemporal_store(acc[i][j][r] * SC1, &C[(crow + r) * NP + ccol]);
        }
    }
}

// ---------------- solve body (r9-proven, 286 us config): 4 samples / 256 thr
__device__ __forceinline__ void solve_body(
    char* smem, const float* __restrict__ z, const float* __restrict__ bz,
    const float* __restrict__ gout, const float* __restrict__ cq,
    const float* __restrict__ G, float* __restrict__ rw, float* __restrict__ kc,
    int solveStart, int sb)
{
    float (*Vs)[2048] = (float (*)[2048])smem;   // 32 KB

    const int tid  = threadIdx.x;
    const int lane = tid & 63;
    const int smp  = tid >> 6;
    const int sl   = (sb << 2) + smp;
    const size_t s = (size_t)solveStart + sl;
    const float c  = 1.0f + TEPS;

    const float* Grow = G + (size_t)sl * NP;

    const float4* G4 = (const float4*)Grow;
    float4* Vw = (float4*)&Vs[smp][0];
    #pragma unroll
    for (int it = 0; it < 8; ++it) {
        int idx = it * 64 + lane;
        if (idx < NTRI / 4) Vw[idx] = G4[idx];
    }

    const float4* zr = (const float4*)(z + s * 512);
    float4 za = zr[lane];
    float4 zb = zr[64 + lane];
    float r2 = za.x * za.x + za.y * za.y + za.z * za.z + za.w * za.w
             + zb.x * zb.x + zb.y * zb.y + zb.z * zb.z + zb.w * zb.w;
    #pragma unroll
    for (int o = 32; o; o >>= 1) r2 += __shfl_xor(r2, o);

    float qv = bz[lane] + Grow[Q0 + lane];
    #pragma unroll
    for (int r = 0; r < 8; ++r) {
        float a = Grow[U0 + r];
        float b = Grow[V0 + r];
        qv = fmaf(a * b, gout[r * 64 + lane], qv);
    }
    const float qorig = qv;

    const int ibase = (lane * (127 - lane)) / 2 - lane - 1;
    f32x2 m2[32];
    #pragma unroll
    for (int j = 0; j < 64; ++j) {
        const int jbase = (j * (127 - j)) / 2 - j - 1;
        int addr = (j > lane) ? (ibase + j) : (jbase + lane);
        addr = (j == lane) ? 0 : addr;
        float v = Vs[smp][addr];
        float val = (j > lane) ? v : -v;
        val = (j == lane) ? 0.0f : val;
        if (j & 1) m2[j >> 1].y = val; else m2[j >> 1].x = val;
    }

    float myinv = 0.0f;
    #pragma unroll
    for (int k = 0; k < 64; ++k) {
        const int kp = k >> 1;
        const float mk = (k & 1) ? m2[kp].y : m2[kp].x;
        float piv = rdlane(mk, k) + c;
        float inv = frcp(piv);
        bool isk = (lane == k);
        float f = isk ? 0.0f : mk * inv;
        myinv = isk ? inv : myinv;
        const float nf = -f;
        const f32x2 nf2 = {nf, nf};
        qv = fmaf(nf, rdlane(qv, k), qv);
        if ((k & 1) == 0)
            m2[kp].y = fmaf(nf, rdlane(m2[kp].y, k), m2[kp].y);
        #pragma unroll
        for (int p = kp + 1; p < 32; ++p) {
            f32x2 bc;
            bc.x = rdlane(m2[p].x, k);
            bc.y = rdlane(m2[p].y, k);
            m2[p] = __builtin_elementwise_fma(nf2, bc, m2[p]);
        }
        if (k & 1) m2[kp].y = f; else m2[kp].x = f;
    }
    float y = qv * myinv;

    double rr_d = (double)qorig - (double)c * (double)y;
    #pragma unroll
    for (int j = 0; j < 64; ++j) {
        const int jbase = (j * (127 - j)) / 2 - j - 1;
        int addr = (j > lane) ? (ibase + j) : (jbase + lane);
        addr = (j == lane) ? 0 : addr;
        float v = Vs[smp][addr];
        float val = (j > lane) ? v : -v;
        val = (j == lane) ? 0.0f : val;
        rr_d -= (double)val * (double)rdlane(y, j);
    }
    float rf = (float)rr_d;
    #pragma unroll
    for (int k = 0; k < 64; ++k) {
        const float mk = (k & 1) ? m2[k >> 1].y : m2[k >> 1].x;
        rf = fmaf(-mk, rdlane(rf, k), rf);
    }
    y = fmaf(rf, myinv, y);

    const float v = 2.0f * c * y - qorig;

    float sc = 0.0f;
    const float4* cr = (const float4*)(cq + (size_t)lane * 64);
    #pragma unroll
    for (int j4 = 0; j4 < 16; ++j4) {
        float4 c4 = cr[j4];
        sc = fmaf(c4.x, rdlane(v, 4 * j4 + 0), sc);
        sc = fmaf(c4.y, rdlane(v, 4 * j4 + 1), sc);
        sc = fmaf(c4.z, rdlane(v, 4 * j4 + 2), sc);
        sc = fmaf(c4.w, rdlane(v, 4 * j4 + 3), sc);
    }

    float denom = fmaxf(1.0f - r2, 1e-3f);
    float tau   = fmaxf(4.0f * denom, 0.01f);
    float logit = sc * frcp(tau);
    float mx = logit;
    #pragma unroll
    for (int o = 32; o; o >>= 1) mx = fmaxf(mx, __shfl_xor(mx, o));
    float e = __expf(logit - mx);
    float sum = e;
    #pragma unroll
    for (int o = 32; o; o >>= 1) sum += __shfl_xor(sum, o);
    rw[s * 64 + lane] = e * frcp(sum);

    unsigned long long bal = __ballot(logit == mx);
    if (lane == 0) kc[s] = (float)(__ffsll(bal) - 1);
}

// ---------------- fused: blocks [0,gemmBlocks) gemm chunk i; rest solve chunk i-1.
// GEMM (MFMA+HBM pipes) and solve (VALU pipe) co-schedule on the device (m114)
// -> overlaps the two dominant, pipe-disjoint phases that stream order
// otherwise serializes. Chunk i-1's G is complete by stream ordering.
__global__ __launch_bounds__(256) void fused_kernel(
    const u16* __restrict__ A, const u16* __restrict__ Bw, float* __restrict__ Cg,
    int gemmBlocks,
    const float* __restrict__ z, const float* __restrict__ bz,
    const float* __restrict__ gout, const float* __restrict__ cq,
    const float* __restrict__ Gp, float* __restrict__ rw, float* __restrict__ kc,
    int solveStart)
{
    __shared__ alignas(16) char smem[32768];
    if ((int)blockIdx.x < gemmBlocks)
        gemm_body(smem, A, Bw, Cg, gemmBlocks, blockIdx.x);
    else
        solve_body(smem, z, bz, gout, cq, Gp, rw, kc, solveStart,
                   blockIdx.x - gemmBlocks);
}

// ---------------- standalone solve (pipeline tail)
__global__ __launch_bounds__(256) void solve_kernel(
    const float* __restrict__ z, const float* __restrict__ bz,
    const float* __restrict__ gout, const float* __restrict__ cq,
    const float* __restrict__ G, float* __restrict__ rw, float* __restrict__ kc,
    int solveStart)
{
    __shared__ alignas(16) char smem[32768];
    solve_body(smem, z, bz, gout, cq, G, rw, kc, solveStart, blockIdx.x);
}

// ---------------- host orchestration
extern "C" void kernel_launch(void* const* d_in, const int* in_sizes, int n_in,
                              void* d_out, int out_size, void* d_ws, size_t ws_size,
                              hipStream_t stream)
{
    const float* z    = (const float*)d_in[0];
    const float* wz   = (const float*)d_in[1];
    const float* bz   = (const float*)d_in[2];
    const float* gout = (const float*)d_in[3];
    const float* gu   = (const float*)d_in[4];
    const float* gv   = (const float*)d_in[5];
    const float* cq   = (const float*)d_in[6];
    const float* wt   = (const float*)d_in[7];

    float* rw = (float*)d_out;
    float* kc = rw + (size_t)B_N * NC_N;

    const size_t whl_b = (size_t)NP * KP * 2;          // ~6.7 MB
    const size_t zhl_b = (size_t)B_N * KP * 2;         // ~100.7 MB

    int CB = 4096;                                     // pipeline chunk
    while (CB > 512) {
        size_t need = whl_b + zhl_b + 2 * (size_t)CB * NP * 4;
        if (need <= ws_size) break;
        CB >>= 1;
    }
    const int nchunks = B_N / CB;
    const int GB = (CB / 128) * (NP / 128);            // gemm blocks per chunk
    const int SBLK = CB / 4;                           // solve blocks per chunk

    u16*   w_hl = (u16*)d_ws;
    u16*   z_hl = (u16*)((char*)d_ws + whl_b);
    float* G0   = (float*)((char*)d_ws + whl_b + zhl_b);
    float* G1   = G0 + (size_t)CB * NP;

    prep_w_kernel<<<NP / 2, 256, 0, stream>>>(wt, wz, gu, gv, w_hl);
    prep_z_kernel<<<B_N / 2, 256, 0, stream>>>(z, z_hl);

    for (int i = 0; i < nchunks; ++i) {
        float* Gc = (i & 1) ? G1 : G0;
        const float* Gp = (i & 1) ? G0 : G1;
        const u16* Ac = z_hl + (size_t)i * CB * KP;
        if (i == 0) {
            fused_kernel<<<GB, 256, 0, stream>>>(
                Ac, w_hl, Gc, GB, z, bz, gout, cq, Gp, rw, kc, 0);
        } else {
            fused_kernel<<<GB + SBLK, 256, 0, stream>>>(
                Ac, w_hl, Gc, GB, z, bz, gout, cq, Gp, rw, kc, (i - 1) * CB);
        }
    }
    // tail: solve the last chunk
    const float* Glast = ((nchunks - 1) & 1) ? G1 : G0;
    solve_kernel<<<SBLK, 256, 0, stream>>>(
        z, bz, gout, cq, Glast, rw, kc, (nchunks - 1) * CB);
}

// Round 14
// 757.563 us; speedup vs baseline: 1.9945x; 1.8040x over previous
//
#include <hip/hip_runtime.h>
#include <cstdint>
#include <cstddef>
#include <cmath>

#define B_N   32768
#define D_DIM 512
#define NC_N  64
#define NTRI  2016      /* packed upper-triangle skew columns (i<j) */
#define NP    2176      /* 2016 tri + 64 w_z + 8 g_u + 8 g_v + 80 pad (17*128) */
#define Q0    2016
#define U0    2080
#define V0    2088
#define KP    1536      /* [zh|zh|zl] . [wh|wl|wh] f16 split, K=3*512 */
#define KT_N  24        /* KP/64 */
#define TEPS  1e-3f
#define SC1   0x1.0p-22f  /* undo 2^11 * 2^11 input scaling */

typedef unsigned short u16;
typedef _Float16 f16;
typedef __attribute__((ext_vector_type(8))) _Float16 f16x8;
typedef __attribute__((ext_vector_type(4))) float f32x4;
typedef __attribute__((ext_vector_type(2))) float f32x2;

__device__ __forceinline__ u16 h_of(float x) { f16 h = (f16)x; return *reinterpret_cast<u16*>(&h); }
__device__ __forceinline__ float f_of_h(u16 u) { f16 h = *reinterpret_cast<f16*>(&u); return (float)h; }
__device__ __forceinline__ float rdlane(float x, int k) {
    return __int_as_float(__builtin_amdgcn_readlane(__float_as_int(x), k));
}
__device__ __forceinline__ float frcp(float x) {
    float r = __builtin_amdgcn_rcpf(x);
    return r * fmaf(-x, r, 2.0f);
}
__device__ __forceinline__ void split2(float x, u16& h, u16& l) {
    float s = x * 2048.0f;           // exact
    h = h_of(s);
    l = h_of(s - f_of_h(h));
}

// ---------------- prep: B' rows -> [NP][1536] f16 = [wh|wl|wh]
// rows 0..2015 (packed pair p <-> (i<j)): 0.25*(w_t[j*64+i] - w_t[i*64+j]).
// rows 2016..2079: w_z ; 2080..2087: g_u ; 2088..2095: g_v ; rest 0.
__global__ __launch_bounds__(256) void prep_w_kernel(
    const float* __restrict__ wt, const float* __restrict__ wz,
    const float* __restrict__ gu, const float* __restrict__ gv,
    u16* __restrict__ dst)
{
    int t = blockIdx.x * 256 + threadIdx.x;
    if (t >= NP * 128) return;
    int row = t >> 7;
    int c4  = (t & 127) << 2;
    float4 v = make_float4(0.f, 0.f, 0.f, 0.f);
    if (row < NTRI) {
        int p = row;
        int i = (int)((127.0 - sqrt(16129.0 - 8.0 * (double)p)) * 0.5);
        if (i < 0) i = 0; if (i > 62) i = 62;
        while (i > 0 && (i * (127 - i)) / 2 > p) --i;
        while (((i + 1) * (126 - i)) / 2 <= p) ++i;
        int j = p - (i * (127 - i)) / 2 + i + 1;
        float4 a = *(const float4*)(wt + (size_t)(j * 64 + i) * 512 + c4);
        float4 b = *(const float4*)(wt + (size_t)(i * 64 + j) * 512 + c4);
        v.x = 0.25f * (a.x - b.x);
        v.y = 0.25f * (a.y - b.y);
        v.z = 0.25f * (a.z - b.z);
        v.w = 0.25f * (a.w - b.w);
    }
    else if (row < U0)        v = *(const float4*)(wz + (size_t)(row - Q0) * 512 + c4);
    else if (row < V0)        v = *(const float4*)(gu + (size_t)(row - U0) * 512 + c4);
    else if (row < V0 + 8)    v = *(const float4*)(gv + (size_t)(row - V0) * 512 + c4);
    ushort4 hv, lv;
    split2(v.x, hv.x, lv.x); split2(v.y, hv.y, lv.y);
    split2(v.z, hv.z, lv.z); split2(v.w, hv.w, lv.w);
    u16* base = dst + (size_t)row * KP + c4;
    *(ushort4*)(base)        = hv;
    *(ushort4*)(base + 512)  = lv;
    *(ushort4*)(base + 1024) = hv;
}

// ---------------- prep: z chunk -> [CB][1536] f16 = [zh|zh|zl]
__global__ __launch_bounds__(256) void prep_z_kernel(
    const float* __restrict__ z, u16* __restrict__ dst, int chunkStart, int CB)
{
    int t = blockIdx.x * 256 + threadIdx.x;
    if (t >= CB * 128) return;
    int row = t >> 7;
    int c4  = (t & 127) << 2;
    float4 v = *(const float4*)(z + (size_t)(chunkStart + row) * 512 + c4);
    ushort4 hv, lv;
    split2(v.x, hv.x, lv.x); split2(v.y, hv.y, lv.y);
    split2(v.z, hv.z, lv.z); split2(v.w, hv.w, lv.w);
    u16* base = dst + (size_t)row * KP + c4;
    *(ushort4*)(base)        = hv;
    *(ushort4*)(base + 512)  = hv;
    *(ushort4*)(base + 1024) = lv;
}

// ---------------- GEMM: C[CB][NP] f32 = (A[CB][KP] * B[NP][KP]^T) * 2^-22
// r9-proven 128x128 tile, BK=64, 4 waves (2x2), 16x16x32 f16 MFMA,
// global_load_lds(16B), bijective XCD swizzle, non-temporal C stores.
__global__ __launch_bounds__(256) void gemm_kernel(
    const u16* __restrict__ A, const u16* __restrict__ Bw, float* __restrict__ C)
{
    __shared__ alignas(16) u16 As[128 * 64];
    __shared__ alignas(16) u16 Bs[128 * 64];
    const int t    = threadIdx.x;
    const int lane = t & 63;
    const int w    = t >> 6;
    const int wr   = w >> 1, wc = w & 1;

    const int nwg = gridDim.x * gridDim.y;
    int flat = blockIdx.y * gridDim.x + blockIdx.x;
    if ((nwg & 7) == 0) {
        const int cpx = nwg >> 3;
        flat = (flat & 7) * cpx + (flat >> 3);
    }
    const int bx = flat % gridDim.x;
    const int by = flat / gridDim.x;
    const size_t m0 = (size_t)by * 128;
    const size_t n0 = (size_t)bx * 128;

    const char* Ab = (const char*)A  + (m0 + (size_t)(t >> 3)) * (KP * 2) + (size_t)(t & 7) * 16;
    const char* Bb = (const char*)Bw + (n0 + (size_t)(t >> 3)) * (KP * 2) + (size_t)(t & 7) * 16;
    char* AsB = (char*)&As[0];
    char* BsB = (char*)&Bs[0];

    f32x4 acc[4][4];
    #pragma unroll
    for (int i = 0; i < 4; ++i)
        #pragma unroll
        for (int j = 0; j < 4; ++j)
            acc[i][j] = (f32x4){0.f, 0.f, 0.f, 0.f};

    const int lr = lane & 15;
    const int lk = (lane >> 4) * 8;

    #pragma unroll 1
    for (int kt = 0; kt < KT_N; ++kt) {
        __syncthreads();
        const size_t koff = (size_t)kt * 128;
        #pragma unroll
        for (int cc = 0; cc < 4; ++cc) {
            __builtin_amdgcn_global_load_lds(
                (const __attribute__((address_space(1))) unsigned int*)(Ab + (size_t)cc * (32 * KP * 2) + koff),
                (__attribute__((address_space(3))) unsigned int*)(AsB + cc * 4096 + w * 1024),
                16, 0, 0);
            __builtin_amdgcn_global_load_lds(
                (const __attribute__((address_space(1))) unsigned int*)(Bb + (size_t)cc * (32 * KP * 2) + koff),
                (__attribute__((address_space(3))) unsigned int*)(BsB + cc * 4096 + w * 1024),
                16, 0, 0);
        }
        asm volatile("s_waitcnt vmcnt(0)" ::: "memory");
        __syncthreads();
        #pragma unroll
        for (int kk = 0; kk < 64; kk += 32) {
            f16x8 af[4], bf[4];
            #pragma unroll
            for (int i = 0; i < 4; ++i) {
                af[i] = *(const f16x8*)&As[(wr * 64 + i * 16 + lr) * 64 + kk + lk];
                bf[i] = *(const f16x8*)&Bs[(wc * 64 + i * 16 + lr) * 64 + kk + lk];
            }
            #pragma unroll
            for (int i = 0; i < 4; ++i)
                #pragma unroll
                for (int j = 0; j < 4; ++j)
                    acc[i][j] = __builtin_amdgcn_mfma_f32_16x16x32_f16(af[i], bf[j], acc[i][j], 0, 0, 0);
        }
    }
    const int fq = lane >> 4;
    const int fr = lane & 15;
    #pragma unroll
    for (int i = 0; i < 4; ++i) {
        #pragma unroll
        for (int j = 0; j < 4; ++j) {
            size_t crow = m0 + (size_t)(wr * 64 + i * 16 + fq * 4);
            size_t ccol = n0 + (size_t)(wc * 64 + j * 16 + fr);
            #pragma unroll
            for (int r = 0; r < 4; ++r)
                __builtin_nontemporal_store(acc[i][j][r] * SC1, &C[(crow + r) * NP + ccol]);
        }
    }
}

// ---------------- per-sample Cayley solve + router (r9-proven body)
// 4 samples per 256-thread block (1 wave each). LDS-staged packed triangle,
// per-row gather, packed-f32 Gauss-Jordan, f64-residual refinement,
// v = u^T q = 2c*y - q, scores = cq @ v, softmax/argmax.
__global__ __launch_bounds__(256) void solve_kernel(
    const float* __restrict__ z, const float* __restrict__ bz,
    const float* __restrict__ gout, const float* __restrict__ cq,
    const float* __restrict__ G, float* __restrict__ rw, float* __restrict__ kc,
    int chunkStart)
{
    const int tid  = threadIdx.x;
    const int lane = tid & 63;
    const int smp  = tid >> 6;
    const int sl   = (blockIdx.x << 2) + smp;
    const size_t s = (size_t)chunkStart + sl;
    const float c  = 1.0f + TEPS;

    __shared__ alignas(16) float Vs[4][2048];

    const float* Grow = G + (size_t)sl * NP;

    const float4* G4 = (const float4*)Grow;
    float4* Vw = (float4*)&Vs[smp][0];
    #pragma unroll
    for (int it = 0; it < 8; ++it) {
        int idx = it * 64 + lane;
        if (idx < NTRI / 4) Vw[idx] = G4[idx];
    }

    const float4* zr = (const float4*)(z + s * 512);
    float4 za = zr[lane];
    float4 zb = zr[64 + lane];
    float r2 = za.x * za.x + za.y * za.y + za.z * za.z + za.w * za.w
             + zb.x * zb.x + zb.y * zb.y + zb.z * zb.z + zb.w * zb.w;
    #pragma unroll
    for (int o = 32; o; o >>= 1) r2 += __shfl_xor(r2, o);

    float qv = bz[lane] + Grow[Q0 + lane];
    #pragma unroll
    for (int r = 0; r < 8; ++r) {
        float a = Grow[U0 + r];
        float b = Grow[V0 + r];
        qv = fmaf(a * b, gout[r * 64 + lane], qv);
    }
    const float qorig = qv;

    const int ibase = (lane * (127 - lane)) / 2 - lane - 1;
    f32x2 m2[32];
    #pragma unroll
    for (int j = 0; j < 64; ++j) {
        const int jbase = (j * (127 - j)) / 2 - j - 1;
        int addr = (j > lane) ? (ibase + j) : (jbase + lane);
        addr = (j == lane) ? 0 : addr;
        float v = Vs[smp][addr];
        float val = (j > lane) ? v : -v;
        val = (j == lane) ? 0.0f : val;
        if (j & 1) m2[j >> 1].y = val; else m2[j >> 1].x = val;
    }

    float myinv = 0.0f;
    #pragma unroll
    for (int k = 0; k < 64; ++k) {
        const int kp = k >> 1;
        const float mk = (k & 1) ? m2[kp].y : m2[kp].x;
        float piv = rdlane(mk, k) + c;
        float inv = frcp(piv);
        bool isk = (lane == k);
        float f = isk ? 0.0f : mk * inv;
        myinv = isk ? inv : myinv;
        const float nf = -f;
        const f32x2 nf2 = {nf, nf};
        qv = fmaf(nf, rdlane(qv, k), qv);
        if ((k & 1) == 0)
            m2[kp].y = fmaf(nf, rdlane(m2[kp].y, k), m2[kp].y);
        #pragma unroll
        for (int p = kp + 1; p < 32; ++p) {
            f32x2 bc;
            bc.x = rdlane(m2[p].x, k);
            bc.y = rdlane(m2[p].y, k);
            m2[p] = __builtin_elementwise_fma(nf2, bc, m2[p]);
        }
        if (k & 1) m2[kp].y = f; else m2[kp].x = f;
    }
    float y = qv * myinv;

    double rr_d = (double)qorig - (double)c * (double)y;
    #pragma unroll
    for (int j = 0; j < 64; ++j) {
        const int jbase = (j * (127 - j)) / 2 - j - 1;
        int addr = (j > lane) ? (ibase + j) : (jbase + lane);
        addr = (j == lane) ? 0 : addr;
        float v = Vs[smp][addr];
        float val = (j > lane) ? v : -v;
        val = (j == lane) ? 0.0f : val;
        rr_d -= (double)val * (double)rdlane(y, j);
    }
    float rf = (float)rr_d;
    #pragma unroll
    for (int k = 0; k < 64; ++k) {
        const float mk = (k & 1) ? m2[k >> 1].y : m2[k >> 1].x;
        rf = fmaf(-mk, rdlane(rf, k), rf);
    }
    y = fmaf(rf, myinv, y);

    const float v = 2.0f * c * y - qorig;

    float sc = 0.0f;
    const float4* cr = (const float4*)(cq + (size_t)lane * 64);
    #pragma unroll
    for (int j4 = 0; j4 < 16; ++j4) {
        float4 c4 = cr[j4];
        sc = fmaf(c4.x, rdlane(v, 4 * j4 + 0), sc);
        sc = fmaf(c4.y, rdlane(v, 4 * j4 + 1), sc);
        sc = fmaf(c4.z, rdlane(v, 4 * j4 + 2), sc);
        sc = fmaf(c4.w, rdlane(v, 4 * j4 + 3), sc);
    }

    float denom = fmaxf(1.0f - r2, 1e-3f);
    float tau   = fmaxf(4.0f * denom, 0.01f);
    float logit = sc * frcp(tau);
    float mx = logit;
    #pragma unroll
    for (int o = 32; o; o >>= 1) mx = fmaxf(mx, __shfl_xor(mx, o));
    float e = __expf(logit - mx);
    float sum = e;
    #pragma unroll
    for (int o = 32; o; o >>= 1) sum += __shfl_xor(sum, o);
    rw[s * 64 + lane] = e * frcp(sum);

    unsigned long long bal = __ballot(logit == mx);
    if (lane == 0) kc[s] = (float)(__ffsll(bal) - 1);
}

// ---------------- host orchestration
// CB capped at 8192: G chunk = 71 MB -> G + A-panel + B-panel (~103 MB) stay
// L3-resident, so the solve reads L3-hot G and the gemm C-writes don't thrash
// Infinity Cache. (r9's CB=32768 made G=285 MB > 256 MB L3 -> solve re-read
// from HBM.)
extern "C" void kernel_launch(void* const* d_in, const int* in_sizes, int n_in,
                              void* d_out, int out_size, void* d_ws, size_t ws_size,
                              hipStream_t stream)
{
    const float* z    = (const float*)d_in[0];
    const float* wz   = (const float*)d_in[1];
    const float* bz   = (const float*)d_in[2];
    const float* gout = (const float*)d_in[3];
    const float* gu   = (const float*)d_in[4];
    const float* gv   = (const float*)d_in[5];
    const float* cq   = (const float*)d_in[6];
    const float* wt   = (const float*)d_in[7];

    float* rw = (float*)d_out;
    float* kc = rw + (size_t)B_N * NC_N;

    const size_t whl_b = (size_t)NP * KP * 2;   // ~6.7 MB
    int CB = 128;
    const int cands[7] = {8192, 4096, 2048, 1024, 512, 256, 128};
    for (int i = 0; i < 7; ++i) {
        size_t need = whl_b + (size_t)cands[i] * ((size_t)KP * 2 + (size_t)NP * 4);
        if (need <= ws_size) { CB = cands[i]; break; }
    }

    u16*   w_hl = (u16*)d_ws;
    u16*   z_hl = (u16*)((char*)d_ws + whl_b);
    float* G    = (float*)((char*)d_ws + whl_b + (size_t)CB * KP * 2);

    prep_w_kernel<<<NP / 2, 256, 0, stream>>>(wt, wz, gu, gv, w_hl);
    for (int cs = 0; cs < B_N; cs += CB) {
        prep_z_kernel<<<CB / 2, 256, 0, stream>>>(z, z_hl, cs, CB);
        gemm_kernel<<<dim3(NP / 128, CB / 128), 256, 0, stream>>>(z_hl, w_hl, G);
        solve_kernel<<<CB / 4, 256, 0, stream>>>(z, bz, gout, cq, G, rw, kc, cs);
    }
}

// Round 15
// 690.219 us; speedup vs baseline: 2.1891x; 1.0976x over previous
//
#include <hip/hip_runtime.h>
#include <cstdint>
#include <cstddef>
#include <cmath>

#define B_N   32768
#define D_DIM 512
#define NC_N  64
#define NTRI  2016      /* packed upper-triangle skew columns (i<j) */
#define NP    2176      /* 2016 tri + 64 w_z + 8 g_u + 8 g_v + 80 pad (17*128) */
#define Q0    2016
#define U0    2080
#define V0    2088
#define KP    1536      /* [zh|zh|zl] . [wh|wl|wh] f16 split, K=3*512 */
#define KT_N  24        /* KP/64 */
#define TEPS  1e-3f
#define SC1   0x1.0p-22f  /* undo 2^11 * 2^11 input scaling */

typedef unsigned short u16;
typedef _Float16 f16;
typedef __attribute__((ext_vector_type(8))) _Float16 f16x8;
typedef __attribute__((ext_vector_type(4))) float f32x4;
typedef __attribute__((ext_vector_type(2))) float f32x2;

__device__ __forceinline__ u16 h_of(float x) { f16 h = (f16)x; return *reinterpret_cast<u16*>(&h); }
__device__ __forceinline__ float f_of_h(u16 u) { f16 h = *reinterpret_cast<f16*>(&u); return (float)h; }
__device__ __forceinline__ float rdlane(float x, int k) {
    return __int_as_float(__builtin_amdgcn_readlane(__float_as_int(x), k));
}
__device__ __forceinline__ float frcp(float x) {
    float r = __builtin_amdgcn_rcpf(x);
    return r * fmaf(-x, r, 2.0f);
}
__device__ __forceinline__ void split2(float x, u16& h, u16& l) {
    float s = x * 2048.0f;           // exact
    h = h_of(s);
    l = h_of(s - f_of_h(h));
}

// ---------------- prep: B' rows -> [NP][1536] f16 = [wh|wl|wh]
// rows 0..2015 (packed pair p <-> (i<j)): 0.25*(w_t[j*64+i] - w_t[i*64+j]).
// rows 2016..2079: w_z ; 2080..2087: g_u ; 2088..2095: g_v ; rest 0.
__global__ __launch_bounds__(256) void prep_w_kernel(
    const float* __restrict__ wt, const float* __restrict__ wz,
    const float* __restrict__ gu, const float* __restrict__ gv,
    u16* __restrict__ dst)
{
    int t = blockIdx.x * 256 + threadIdx.x;
    if (t >= NP * 128) return;
    int row = t >> 7;
    int c4  = (t & 127) << 2;
    float4 v = make_float4(0.f, 0.f, 0.f, 0.f);
    if (row < NTRI) {
        int p = row;
        int i = (int)((127.0 - sqrt(16129.0 - 8.0 * (double)p)) * 0.5);
        if (i < 0) i = 0; if (i > 62) i = 62;
        while (i > 0 && (i * (127 - i)) / 2 > p) --i;
        while (((i + 1) * (126 - i)) / 2 <= p) ++i;
        int j = p - (i * (127 - i)) / 2 + i + 1;
        float4 a = *(const float4*)(wt + (size_t)(j * 64 + i) * 512 + c4);
        float4 b = *(const float4*)(wt + (size_t)(i * 64 + j) * 512 + c4);
        v.x = 0.25f * (a.x - b.x);
        v.y = 0.25f * (a.y - b.y);
        v.z = 0.25f * (a.z - b.z);
        v.w = 0.25f * (a.w - b.w);
    }
    else if (row < U0)        v = *(const float4*)(wz + (size_t)(row - Q0) * 512 + c4);
    else if (row < V0)        v = *(const float4*)(gu + (size_t)(row - U0) * 512 + c4);
    else if (row < V0 + 8)    v = *(const float4*)(gv + (size_t)(row - V0) * 512 + c4);
    ushort4 hv, lv;
    split2(v.x, hv.x, lv.x); split2(v.y, hv.y, lv.y);
    split2(v.z, hv.z, lv.z); split2(v.w, hv.w, lv.w);
    u16* base = dst + (size_t)row * KP + c4;
    *(ushort4*)(base)        = hv;
    *(ushort4*)(base + 512)  = lv;
    *(ushort4*)(base + 1024) = hv;
}

// ---------------- prep: z chunk -> [CB][1536] f16 = [zh|zh|zl]
__global__ __launch_bounds__(256) void prep_z_kernel(
    const float* __restrict__ z, u16* __restrict__ dst, int chunkStart, int CB)
{
    int t = blockIdx.x * 256 + threadIdx.x;
    if (t >= CB * 128) return;
    int row = t >> 7;
    int c4  = (t & 127) << 2;
    float4 v = *(const float4*)(z + (size_t)(chunkStart + row) * 512 + c4);
    ushort4 hv, lv;
    split2(v.x, hv.x, lv.x); split2(v.y, hv.y, lv.y);
    split2(v.z, hv.z, lv.z); split2(v.w, hv.w, lv.w);
    u16* base = dst + (size_t)row * KP + c4;
    *(ushort4*)(base)        = hv;
    *(ushort4*)(base + 512)  = hv;
    *(ushort4*)(base + 1024) = lv;
}

// ---------------- GEMM: C[CB][NP] f32 = (A[CB][KP] * B[NP][KP]^T) * 2^-22
// r9-proven 128x128 tile, BK=64, 4 waves (2x2), 16x16x32 f16 MFMA,
// global_load_lds(16B), bijective XCD swizzle, non-temporal C stores.
__global__ __launch_bounds__(256) void gemm_kernel(
    const u16* __restrict__ A, const u16* __restrict__ Bw, float* __restrict__ C)
{
    __shared__ alignas(16) u16 As[128 * 64];
    __shared__ alignas(16) u16 Bs[128 * 64];
    const int t    = threadIdx.x;
    const int lane = t & 63;
    const int w    = t >> 6;
    const int wr   = w >> 1, wc = w & 1;

    const int nwg = gridDim.x * gridDim.y;
    int flat = blockIdx.y * gridDim.x + blockIdx.x;
    if ((nwg & 7) == 0) {
        const int cpx = nwg >> 3;
        flat = (flat & 7) * cpx + (flat >> 3);
    }
    const int bx = flat % gridDim.x;
    const int by = flat / gridDim.x;
    const size_t m0 = (size_t)by * 128;
    const size_t n0 = (size_t)bx * 128;

    const char* Ab = (const char*)A  + (m0 + (size_t)(t >> 3)) * (KP * 2) + (size_t)(t & 7) * 16;
    const char* Bb = (const char*)Bw + (n0 + (size_t)(t >> 3)) * (KP * 2) + (size_t)(t & 7) * 16;
    char* AsB = (char*)&As[0];
    char* BsB = (char*)&Bs[0];

    f32x4 acc[4][4];
    #pragma unroll
    for (int i = 0; i < 4; ++i)
        #pragma unroll
        for (int j = 0; j < 4; ++j)
            acc[i][j] = (f32x4){0.f, 0.f, 0.f, 0.f};

    const int lr = lane & 15;
    const int lk = (lane >> 4) * 8;

    #pragma unroll 1
    for (int kt = 0; kt < KT_N; ++kt) {
        __syncthreads();
        const size_t koff = (size_t)kt * 128;
        #pragma unroll
        for (int cc = 0; cc < 4; ++cc) {
            __builtin_amdgcn_global_load_lds(
                (const __attribute__((address_space(1))) unsigned int*)(Ab + (size_t)cc * (32 * KP * 2) + koff),
                (__attribute__((address_space(3))) unsigned int*)(AsB + cc * 4096 + w * 1024),
                16, 0, 0);
            __builtin_amdgcn_global_load_lds(
                (const __attribute__((address_space(1))) unsigned int*)(Bb + (size_t)cc * (32 * KP * 2) + koff),
                (__attribute__((address_space(3))) unsigned int*)(BsB + cc * 4096 + w * 1024),
                16, 0, 0);
        }
        asm volatile("s_waitcnt vmcnt(0)" ::: "memory");
        __syncthreads();
        #pragma unroll
        for (int kk = 0; kk < 64; kk += 32) {
            f16x8 af[4], bf[4];
            #pragma unroll
            for (int i = 0; i < 4; ++i) {
                af[i] = *(const f16x8*)&As[(wr * 64 + i * 16 + lr) * 64 + kk + lk];
                bf[i] = *(const f16x8*)&Bs[(wc * 64 + i * 16 + lr) * 64 + kk + lk];
            }
            #pragma unroll
            for (int i = 0; i < 4; ++i)
                #pragma unroll
                for (int j = 0; j < 4; ++j)
                    acc[i][j] = __builtin_amdgcn_mfma_f32_16x16x32_f16(af[i], bf[j], acc[i][j], 0, 0, 0);
        }
    }
    const int fq = lane >> 4;
    const int fr = lane & 15;
    #pragma unroll
    for (int i = 0; i < 4; ++i) {
        #pragma unroll
        for (int j = 0; j < 4; ++j) {
            size_t crow = m0 + (size_t)(wr * 64 + i * 16 + fq * 4);
            size_t ccol = n0 + (size_t)(wc * 64 + j * 16 + fr);
            #pragma unroll
            for (int r = 0; r < 4; ++r)
                __builtin_nontemporal_store(acc[i][j][r] * SC1, &C[(crow + r) * NP + ccol]);
        }
    }
}

// ---------------- per-sample Cayley solve + router (r9 body, f32 residual)
// 4 samples per 256-thread block (1 wave each). LDS-staged packed triangle,
// per-row gather, packed-f32 Gauss-Jordan, ONE f32-residual refinement
// (f64 dropped: unrefined y err ~1e-5 rel; f32 residual recovers to ~1e-7,
// 40x margin on the argmax logit budget), v = 2c*y - q, softmax/argmax.
__global__ __launch_bounds__(256) void solve_kernel(
    const float* __restrict__ z, const float* __restrict__ bz,
    const float* __restrict__ gout, const float* __restrict__ cq,
    const float* __restrict__ G, float* __restrict__ rw, float* __restrict__ kc,
    int chunkStart)
{
    const int tid  = threadIdx.x;
    const int lane = tid & 63;
    const int smp  = tid >> 6;
    const int sl   = (blockIdx.x << 2) + smp;
    const size_t s = (size_t)chunkStart + sl;
    const float c  = 1.0f + TEPS;

    __shared__ alignas(16) float Vs[4][2048];

    const float* Grow = G + (size_t)sl * NP;

    const float4* G4 = (const float4*)Grow;
    float4* Vw = (float4*)&Vs[smp][0];
    #pragma unroll
    for (int it = 0; it < 8; ++it) {
        int idx = it * 64 + lane;
        if (idx < NTRI / 4) Vw[idx] = G4[idx];
    }

    const float4* zr = (const float4*)(z + s * 512);
    float4 za = zr[lane];
    float4 zb = zr[64 + lane];
    float r2 = za.x * za.x + za.y * za.y + za.z * za.z + za.w * za.w
             + zb.x * zb.x + zb.y * zb.y + zb.z * zb.z + zb.w * zb.w;
    #pragma unroll
    for (int o = 32; o; o >>= 1) r2 += __shfl_xor(r2, o);

    float qv = bz[lane] + Grow[Q0 + lane];
    #pragma unroll
    for (int r = 0; r < 8; ++r) {
        float a = Grow[U0 + r];
        float b = Grow[V0 + r];
        qv = fmaf(a * b, gout[r * 64 + lane], qv);
    }
    const float qorig = qv;

    const int ibase = (lane * (127 - lane)) / 2 - lane - 1;
    f32x2 m2[32];
    #pragma unroll
    for (int j = 0; j < 64; ++j) {
        const int jbase = (j * (127 - j)) / 2 - j - 1;
        int addr = (j > lane) ? (ibase + j) : (jbase + lane);
        addr = (j == lane) ? 0 : addr;
        float v = Vs[smp][addr];
        float val = (j > lane) ? v : -v;
        val = (j == lane) ? 0.0f : val;
        if (j & 1) m2[j >> 1].y = val; else m2[j >> 1].x = val;
    }

    float myinv = 0.0f;
    #pragma unroll
    for (int k = 0; k < 64; ++k) {
        const int kp = k >> 1;
        const float mk = (k & 1) ? m2[kp].y : m2[kp].x;
        float piv = rdlane(mk, k) + c;
        float inv = frcp(piv);
        bool isk = (lane == k);
        float f = isk ? 0.0f : mk * inv;
        myinv = isk ? inv : myinv;
        const float nf = -f;
        const f32x2 nf2 = {nf, nf};
        qv = fmaf(nf, rdlane(qv, k), qv);
        if ((k & 1) == 0)
            m2[kp].y = fmaf(nf, rdlane(m2[kp].y, k), m2[kp].y);
        #pragma unroll
        for (int p = kp + 1; p < 32; ++p) {
            f32x2 bc;
            bc.x = rdlane(m2[p].x, k);
            bc.y = rdlane(m2[p].y, k);
            m2[p] = __builtin_elementwise_fma(nf2, bc, m2[p]);
        }
        if (k & 1) m2[kp].y = f; else m2[kp].x = f;
    }
    float y = qv * myinv;

    // ---- one refinement step, f32 residual: r = (q - c*y) - S'*y
    // (q - c*y first: both O(0.5), rounding ~3e-8 << r ~ 5e-6)
    float rf = fmaf(-c, y, qorig);
    #pragma unroll
    for (int j = 0; j < 64; ++j) {
        const int jbase = (j * (127 - j)) / 2 - j - 1;
        int addr = (j > lane) ? (ibase + j) : (jbase + lane);
        addr = (j == lane) ? 0 : addr;
        float v = Vs[smp][addr];
        float val = (j > lane) ? v : -v;
        val = (j == lane) ? 0.0f : val;
        rf = fmaf(-val, rdlane(y, j), rf);
    }
    #pragma unroll
    for (int k = 0; k < 64; ++k) {
        const float mk = (k & 1) ? m2[k >> 1].y : m2[k >> 1].x;
        rf = fmaf(-mk, rdlane(rf, k), rf);
    }
    y = fmaf(rf, myinv, y);

    const float v = 2.0f * c * y - qorig;

    float sc = 0.0f;
    const float4* cr = (const float4*)(cq + (size_t)lane * 64);
    #pragma unroll
    for (int j4 = 0; j4 < 16; ++j4) {
        float4 c4 = cr[j4];
        sc = fmaf(c4.x, rdlane(v, 4 * j4 + 0), sc);
        sc = fmaf(c4.y, rdlane(v, 4 * j4 + 1), sc);
        sc = fmaf(c4.z, rdlane(v, 4 * j4 + 2), sc);
        sc = fmaf(c4.w, rdlane(v, 4 * j4 + 3), sc);
    }

    float denom = fmaxf(1.0f - r2, 1e-3f);
    float tau   = fmaxf(4.0f * denom, 0.01f);
    float logit = sc * frcp(tau);
    float mx = logit;
    #pragma unroll
    for (int o = 32; o; o >>= 1) mx = fmaxf(mx, __shfl_xor(mx, o));
    float e = __expf(logit - mx);
    float sum = e;
    #pragma unroll
    for (int o = 32; o; o >>= 1) sum += __shfl_xor(sum, o);
    rw[s * 64 + lane] = e * frcp(sum);

    unsigned long long bal = __ballot(logit == mx);
    if (lane == 0) kc[s] = (float)(__ffsll(bal) - 1);
}

// ---------------- host orchestration (r9 config: single CB=32768 chunk)
extern "C" void kernel_launch(void* const* d_in, const int* in_sizes, int n_in,
                              void* d_out, int out_size, void* d_ws, size_t ws_size,
                              hipStream_t stream)
{
    const float* z    = (const float*)d_in[0];
    const float* wz   = (const float*)d_in[1];
    const float* bz   = (const float*)d_in[2];
    const float* gout = (const float*)d_in[3];
    const float* gu   = (const float*)d_in[4];
    const float* gv   = (const float*)d_in[5];
    const float* cq   = (const float*)d_in[6];
    const float* wt   = (const float*)d_in[7];

    float* rw = (float*)d_out;
    float* kc = rw + (size_t)B_N * NC_N;

    const size_t whl_b = (size_t)NP * KP * 2;   // ~6.7 MB
    int CB = 128;
    const int cands[9] = {32768, 16384, 8192, 4096, 2048, 1024, 512, 256, 128};
    for (int i = 0; i < 9; ++i) {
        size_t need = whl_b + (size_t)cands[i] * ((size_t)KP * 2 + (size_t)NP * 4);
        if (need <= ws_size) { CB = cands[i]; break; }
    }

    u16*   w_hl = (u16*)d_ws;
    u16*   z_hl = (u16*)((char*)d_ws + whl_b);
    float* G    = (float*)((char*)d_ws + whl_b + (size_t)CB * KP * 2);

    prep_w_kernel<<<NP / 2, 256, 0, stream>>>(wt, wz, gu, gv, w_hl);
    for (int cs = 0; cs < B_N; cs += CB) {
        prep_z_kernel<<<CB / 2, 256, 0, stream>>>(z, z_hl, cs, CB);
        gemm_kernel<<<dim3(NP / 128, CB / 128), 256, 0, stream>>>(z_hl, w_hl, G);
        solve_kernel<<<CB / 4, 256, 0, stream>>>(z, bz, gout, cq, G, rw, kc, cs);
    }
}